// Round 9
// baseline (460.640 us; speedup 1.0000x reference)
//
#include <hip/hip_runtime.h>
#include <hip/hip_bf16.h>

// ---------------------------------------------------------------------------
// EnsembleDynamicModel: E=7 MLPs, B=32768, dims 40->256->256->256->128->(32|32)
//
// Round 9: register-resident MLP — zero LDS, zero barriers.
// R0-R8 established that the LDS activation round-trip (C->swish->ds_write->
// barrier->ds_read) and its lockstep phase machine smear 79us of pipe demand
// into 144.6us, and no scheduling/occupancy/barrier variant moves it.
// This round removes the transpose itself:
//   - Operand swap: A = W^T (M=out-neuron), B = activation (N=batch).
//     Wave owns 16 batch cols for the WHOLE net; C col = lane&15 = batch.
//   - Neuron permutation sigma(p) = (mt>>1)*32+(pos>>2)*8+((mt&1)<<2)+(pos&3)
//     baked into pack_w: the value lane (q,l) needs for next-layer B-frag
//     (kt, j) = logical neuron kt*32+q*8+j sits in THAT LANE's acc[2kt+(j>>2)]
//     [j&3]. Handoff = swish + cvt_pk, fully lane-local. No shuffles.
//   - Biases for frag-pair kp are contiguous: bias[kp*32+q*8 .. +8] (float4).
//   - Head uses identity sigma -> natural mu/sig/residual/clamp indexing,
//     branch-free epilogue, dwordx4 stores.
// Waves fully independent: no __shared__, no __syncthreads anywhere.
// Cost: W streams per-wave (4x L2 requests; W L2-resident, L1 catches
// in-phase block waves). Regs: act 32 + acc 64 + window ~= 140 <= 170.
// Tripwire: WRITE_SIZE > ~57MB = spill. Fallback: LDS W-staging on this
// same barrier-free activation skeleton.
// ---------------------------------------------------------------------------

#define NE 7
#define NB 32768
#define PER_E 188416   // packed shorts per ensemble (layout below)

typedef __attribute__((ext_vector_type(8))) short short8;   // 8 x bf16
typedef __attribute__((ext_vector_type(4))) float floatx4;  // MFMA C/D

union S8U { short8 s; unsigned u[4]; };

__device__ __forceinline__ short f2b(float f) {
    union { float f; unsigned u; } c; c.f = f;
    return (short)((c.u + 0x7fffu + ((c.u >> 16) & 1u)) >> 16);
}
__device__ __forceinline__ unsigned pk2(float a, float b) {  // bf16x2 {lo=a,hi=b}
    union { __hip_bfloat162 h; unsigned u; } c;
    c.h = __float22bfloat162_rn(make_float2(a, b));
    return c.u;
}
__device__ __forceinline__ float swish(float v) {
    return v * __builtin_amdgcn_rcpf(1.f + __expf(-v));
}
__device__ __forceinline__ float softplus_stable(float x) {
    return fmaxf(x, 0.f) + __logf(1.f + __expf(-fabsf(x)));
}

// Packed A-operand (W^T) fragments, per ensemble (units: shorts):
//  L0 : off 0      KT=2 NT=16 Kact=40   (sigma-permuted cols)
//  L1 : off 16384  KT=8 NT=16 Kact=256
//  L2 : off 81920  KT=8 NT=16 Kact=256
//  L3 : off 147456 KT=8 NT=8  Kact=256  N=128
//  HD : off 180224 KT=4 NT=4  Kact=128  N=64 identity (mu 0..31 | sig 32..63)
// frag(kt,mt) lane(q,l) j: W[k = kt*32+q*8+j][n], n = sigma(mt,l) or mt*16+l.
__global__ void __launch_bounds__(256) pack_w(
    const float* __restrict__ W0, const float* __restrict__ W1,
    const float* __restrict__ W2, const float* __restrict__ W3,
    const float* __restrict__ Wmu, const float* __restrict__ Wsig,
    short* __restrict__ out)
{
    const int t = threadIdx.x;
    const int b = blockIdx.x;
    const int e = b / 92;
    const int r = b - e * 92;
    const int fid  = r * 4 + (t >> 6);      // 368 frags per ensemble
    const int lane = t & 63, q = lane >> 4, l = lane & 15;

    const float* src = W0;
    int off = 0, Kact = 40, N = 256, NT = 16, kt, mt;
    bool head = false;
    if (fid < 32)       { kt = fid >> 4; mt = fid & 15; }
    else if (fid < 160) { int f = fid - 32;  src = W1; off = 16384;  Kact = 256; kt = f >> 4; mt = f & 15; }
    else if (fid < 288) { int f = fid - 160; src = W2; off = 81920;  Kact = 256; kt = f >> 4; mt = f & 15; }
    else if (fid < 352) { int f = fid - 288; src = W3; off = 147456; Kact = 256; N = 128; NT = 8; kt = f >> 3; mt = f & 7; }
    else                { int f = fid - 352; off = 180224; Kact = 128; N = 64; NT = 4; kt = f >> 2; mt = f & 3; head = true; }

    const int n = head ? (mt * 16 + l)
                       : ((mt >> 1) * 32 + (l >> 2) * 8 + ((mt & 1) << 2) + (l & 3));
    short8 o;
#pragma unroll
    for (int j = 0; j < 8; ++j) {
        const int k = kt * 32 + q * 8 + j;
        float v = 0.f;
        if (k < Kact) {
            if (head) v = (n < 32) ? Wmu[((size_t)e * 128 + k) * 32 + n]
                                   : Wsig[((size_t)e * 128 + k) * 32 + (n - 32)];
            else      v = src[((size_t)e * Kact + k) * N + n];
        }
        o[j] = f2b(v);
    }
    *(short8*)(out + (size_t)e * PER_E + off +
               ((size_t)(kt * NT + mt) * 64 + lane) * 8) = o;
}

// One layer, fully in-register. ain[KT] B-frags in, aout[NT/2] B-frags out.
// acc[mt] rows are physical slots; sigma makes the handoff lane-local:
// aout[kp] = {pk(acc[2kp][0..1]), pk(acc[2kp][2..3]),
//             pk(acc[2kp+1][0..1]), pk(acc[2kp+1][2..3])} after bias+swish.
template<int KT, int NT>
__device__ __forceinline__ void mlp_layer(const short* __restrict__ wfr,
                                          const float* __restrict__ bias,
                                          const short8* ain, short8* aout,
                                          const int lane, const int q) {
    floatx4 acc[NT];
#pragma unroll
    for (int mt = 0; mt < NT; ++mt) acc[mt] = floatx4{0.f, 0.f, 0.f, 0.f};
#pragma unroll
    for (int kt = 0; kt < KT; ++kt) {
#pragma unroll
        for (int mt = 0; mt < NT; ++mt) {
            const short8 wf = *(const short8*)(wfr +
                ((size_t)(kt * NT + mt) * 64 + lane) * 8);
            acc[mt] = __builtin_amdgcn_mfma_f32_16x16x32_bf16(wf, ain[kt], acc[mt], 0, 0, 0);
        }
    }
#pragma unroll
    for (int kp = 0; kp < NT / 2; ++kp) {
        const int mA = 2 * kp, mB = 2 * kp + 1;
        const float4 bA = *(const float4*)(bias + kp * 32 + q * 8);       // sigma base, r contiguous
        const float4 bB = *(const float4*)(bias + kp * 32 + q * 8 + 4);
        S8U t;
        t.u[0] = pk2(swish(acc[mA][0] + bA.x), swish(acc[mA][1] + bA.y));
        t.u[1] = pk2(swish(acc[mA][2] + bA.z), swish(acc[mA][3] + bA.w));
        t.u[2] = pk2(swish(acc[mB][0] + bB.x), swish(acc[mB][1] + bB.y));
        t.u[3] = pk2(swish(acc[mB][2] + bB.z), swish(acc[mB][3] + bB.w));
        aout[kp] = t.s;
    }
}

__global__ void __launch_bounds__(256, 3)
fused_ensemble(const float* __restrict__ state, const float* __restrict__ action,
               const float* __restrict__ b0, const float* __restrict__ b1,
               const float* __restrict__ b2, const float* __restrict__ b3,
               const float* __restrict__ bmu, const float* __restrict__ bsig,
               const float* __restrict__ maxls, const float* __restrict__ minls,
               const short* __restrict__ wpk,
               float* __restrict__ out_mu, float* __restrict__ out_sig) {
    const int tid  = threadIdx.x;
    const int wave = tid >> 6, lane = tid & 63;
    const int q = lane >> 4, l = lane & 15;
    const int bid  = blockIdx.x;
    const int e    = bid >> 9;
    const int batch = ((bid & 511) << 6) + wave * 16 + l;   // this lane's column

    const short* wp = wpk + (size_t)e * PER_E;

    short8 actA[8], actB[8];

    // L0 input B-frags: kt0 = state[batch][q*8..+8]; kt1 = action (q==0) else 0.
    {
        const float4* sp = (const float4*)(state + (size_t)batch * 32 + q * 8);
        const float4 s0 = sp[0], s1 = sp[1];
        S8U t;
        t.u[0] = pk2(s0.x, s0.y); t.u[1] = pk2(s0.z, s0.w);
        t.u[2] = pk2(s1.x, s1.y); t.u[3] = pk2(s1.z, s1.w);
        actB[0] = t.s;
        if (q == 0) {
            const float4* ap = (const float4*)(action + (size_t)batch * 8);
            const float4 a0 = ap[0], a1 = ap[1];
            S8U u;
            u.u[0] = pk2(a0.x, a0.y); u.u[1] = pk2(a0.z, a0.w);
            u.u[2] = pk2(a1.x, a1.y); u.u[3] = pk2(a1.z, a1.w);
            actB[1] = u.s;
        } else {
            actB[1] = short8{0, 0, 0, 0, 0, 0, 0, 0};
        }
    }

    mlp_layer<2, 16>(wp,           b0 + e * 256, actB, actA, lane, q);  // L0
    mlp_layer<8, 16>(wp + 16384,   b1 + e * 256, actA, actB, lane, q);  // L1
    mlp_layer<8, 16>(wp + 81920,   b2 + e * 256, actB, actA, lane, q);  // L2
    mlp_layer<8, 8 >(wp + 147456,  b3 + e * 128, actA, actB, lane, q);  // L3 -> actB[0..3]

    // Head: K=128, N=64 combined (identity layout: mu mts 0,1 | sig mts 2,3).
    floatx4 acc[4];
#pragma unroll
    for (int mt = 0; mt < 4; ++mt) acc[mt] = floatx4{0.f, 0.f, 0.f, 0.f};
    const short* wph = wp + 180224;
#pragma unroll
    for (int kt = 0; kt < 4; ++kt) {
#pragma unroll
        for (int mt = 0; mt < 4; ++mt) {
            const short8 wf = *(const short8*)(wph + ((size_t)(kt * 4 + mt) * 64 + lane) * 8);
            acc[mt] = __builtin_amdgcn_mfma_f32_16x16x32_bf16(wf, actB[kt], acc[mt], 0, 0, 0);
        }
    }
    // mu rows 0..31 (+ residual), dwordx4 per (mt, lane).
#pragma unroll
    for (int mt = 0; mt < 2; ++mt) {
        const int c0 = mt * 16 + q * 4;
        const float4 bv = *(const float4*)(bmu + e * 32 + c0);
        const float4 st = *(const float4*)(state + (size_t)batch * 32 + c0);
        float4 o;
        o.x = acc[mt][0] + bv.x + st.x;
        o.y = acc[mt][1] + bv.y + st.y;
        o.z = acc[mt][2] + bv.z + st.z;
        o.w = acc[mt][3] + bv.w + st.w;
        *(float4*)(out_mu + ((size_t)e * NB + batch) * 32 + c0) = o;
    }
    // sigma rows 32..63: soft_clamp + exp.
#pragma unroll
    for (int mt = 2; mt < 4; ++mt) {
        const int c0 = (mt - 2) * 16 + q * 4;
        const float4 bv = *(const float4*)(bsig + e * 32 + c0);
        const float4 mx = *(const float4*)(maxls + c0);
        const float4 mn = *(const float4*)(minls + c0);
        float4 o;
        {
            float ls = acc[mt][0] + bv.x;
            ls = mx.x - softplus_stable(mx.x - ls);
            ls = mn.x + softplus_stable(ls - mn.x);
            o.x = __expf(ls);
        }
        {
            float ls = acc[mt][1] + bv.y;
            ls = mx.y - softplus_stable(mx.y - ls);
            ls = mn.y + softplus_stable(ls - mn.y);
            o.y = __expf(ls);
        }
        {
            float ls = acc[mt][2] + bv.z;
            ls = mx.z - softplus_stable(mx.z - ls);
            ls = mn.z + softplus_stable(ls - mn.z);
            o.z = __expf(ls);
        }
        {
            float ls = acc[mt][3] + bv.w;
            ls = mx.w - softplus_stable(mx.w - ls);
            ls = mn.w + softplus_stable(ls - mn.w);
            o.w = __expf(ls);
        }
        *(float4*)(out_sig + ((size_t)e * NB + batch) * 32 + c0) = o;
    }
}

extern "C" void kernel_launch(void* const* d_in, const int* in_sizes, int n_in,
                              void* d_out, int out_size, void* d_ws, size_t ws_size,
                              hipStream_t stream) {
    const float* state  = (const float*)d_in[0];
    const float* action = (const float*)d_in[1];
    const float* W0   = (const float*)d_in[2];
    const float* b0   = (const float*)d_in[3];
    const float* W1   = (const float*)d_in[4];
    const float* b1   = (const float*)d_in[5];
    const float* W2   = (const float*)d_in[6];
    const float* b2   = (const float*)d_in[7];
    const float* W3   = (const float*)d_in[8];
    const float* b3   = (const float*)d_in[9];
    const float* Wmu  = (const float*)d_in[10];
    const float* bmu  = (const float*)d_in[11];
    const float* Wsig = (const float*)d_in[12];
    const float* bsig = (const float*)d_in[13];
    const float* maxls = (const float*)d_in[14];
    const float* minls = (const float*)d_in[15];

    short* wpk = (short*)d_ws;                         // packed bf16 weights
    float* out_mu  = (float*)d_out;
    float* out_sig = out_mu + (size_t)NE * NB * 32;

    pack_w<<<NE * 92, 256, 0, stream>>>(W0, W1, W2, W3, Wmu, Wsig, wpk);
    fused_ensemble<<<NE * 512, 256, 0, stream>>>(state, action, b0, b1, b2, b3,
                                                 bmu, bsig, maxls, minls, wpk,
                                                 out_mu, out_sig);
}

// Round 11
// 210.774 us; speedup vs baseline: 2.1855x; 2.1855x over previous
//
#include <hip/hip_runtime.h>
#include <hip/hip_bf16.h>

// ---------------------------------------------------------------------------
// EnsembleDynamicModel: E=7 MLPs, B=32768, dims 40->256->256->256->128->(32|32)
// Fully fused bf16-MFMA kernel (round-0 structure, 144.6us baseline).
//
// Round 11 = Round 10 resubmit (bench died in the Trio harness, no kernel
// verdict; source re-audited: bias algebra exact, sigma closed-form exact with
// safe limits, no OOB). VALU/trans diet on exact-R0:
//  (a) bias-preloaded accumulators: acc[mt][nt] = {b,b,b,b} (bias is one
//      scalar per (nt,lane), invariant over mt/r2), prefetched one layer
//      ahead -> kills ~240 bias-adds/wave; init cost unchanged.
//  (b) closed-form sigma head: exp(soft_clamp(x,mn,mx)) == e^mn + e^mx *
//      rcp(1 + e^(mx-x))  [exact algebra: exp(mn+softplus(z)) = e^mn(1+e^z),
//      e^(mx-softplus(mx-x)) = e^mx/(1+e^(mx-x))]. 6 ops/2 trans per value
//      vs ~17 ops/5 trans. Correct limits: x->-inf -> e^mn; x->+inf ->
//      e^mn+e^mx (= exp(log(e^mn+e^mx)) of the reference).
// Calibrated model: per-SIMD MFMA 16x16x32 ~19.4cyc -> 100K cyc/SIMD = 26%
// of 144.6us (matches MfmaUtil); VALU+trans 198K cyc/SIMD = 57% -> VALU is
// the dominant pipe; cross-wave MFMA/VALU overlap already at 83% combined.
//
// Ledger: R1 spill / R2 LDS-traffic x2 / R3 occupancy / R4 setprio null /
// R5 codegen-invariant / R6 barrier cost / R7 occupancy!=lever / R8 lgkm-only
// null / R9 weight-reuse loss (1 MFMA per frag) -> L2-stream-bound 393us.
//
// Activation layout: pair-interleaved columns: n-tile ntg col c -> physical
// col 32*(ntg>>1) + 2c + (ntg&1); weight packer applies inverse permutation
// to k for layers reading hidden activations. pack_w unchanged.
// ---------------------------------------------------------------------------

#define NE 7
#define NB 32768
#define PER_E 188416   // packed shorts per ensemble
#define HSTRIDE 264    // 256 + 8 pad (shorts)

typedef __attribute__((ext_vector_type(8))) short short8;   // 8 x bf16
typedef __attribute__((ext_vector_type(4))) float floatx4;  // MFMA C/D

__device__ __forceinline__ short f2b(float f) {
    union { float f; unsigned u; } c; c.f = f;
    return (short)((c.u + 0x7fffu + ((c.u >> 16) & 1u)) >> 16);
}
__device__ __forceinline__ unsigned pk2(float a, float b) {  // bf16x2 {lo=a,hi=b}
    union { __hip_bfloat162 h; unsigned u; } c;
    c.h = __float22bfloat162_rn(make_float2(a, b));
    return c.u;
}
__device__ __forceinline__ float swish(float v) {
    return v * __builtin_amdgcn_rcpf(1.f + __expf(-v));
}

// Packed-weight layout per ensemble (units: shorts):
//  L0 : off 0      KT=2 NT=16 Kact=40  N=256
//  L1 : off 16384  KT=8 NT=16 Kact=256 N=256
//  L2 : off 81920  KT=8 NT=16 Kact=256 N=256
//  L3 : off 147456 KT=8 NT=8  Kact=256 N=128
//  HD : off 180224 KT=4 NT=4  Kact=128 N=64   (mu cols 0..31 | sig 32..63)
__global__ void __launch_bounds__(256) pack_w(
    const float* __restrict__ W0, const float* __restrict__ W1,
    const float* __restrict__ W2, const float* __restrict__ W3,
    const float* __restrict__ Wmu, const float* __restrict__ Wsig,
    short* __restrict__ out)
{
    __shared__ float tile[32][65];
    const int t = threadIdx.x;
    int b = blockIdx.x;
    int e = b / 92;
    int r = b - e * 92;
    const float* src = W0;
    int off = 0, Kact = 40, N = 256, NT = 16, kt, ntb;
    bool inv = false, head = false;
    if (r < 8)       { kt = r >> 2; ntb = r & 3; }
    else if (r < 40) { r -= 8;  src = W1; off = 16384;  Kact = 256; kt = r >> 2; ntb = r & 3; inv = true; }
    else if (r < 72) { r -= 40; src = W2; off = 81920;  Kact = 256; kt = r >> 2; ntb = r & 3; inv = true; }
    else if (r < 88) { r -= 72; src = W3; off = 147456; Kact = 256; N = 128; NT = 8; kt = r >> 1; ntb = r & 1; inv = true; }
    else             { r -= 88; off = 180224; Kact = 128; N = 64; NT = 4; kt = r; ntb = 0; inv = true; head = true; }

#pragma unroll
    for (int i = 0; i < 8; ++i) {
        int elem  = t + i * 256;
        int row_l = elem >> 6, col_l = elem & 63;
        int gk = kt * 32 + row_l;
        int gn = ntb * 64 + col_l;
        float v = 0.f;
        if (gk < Kact) {
            if (head) v = (gn < 32) ? Wmu[((size_t)e * 128 + gk) * 32 + gn]
                                    : Wsig[((size_t)e * 128 + gk) * 32 + (gn - 32)];
            else      v = src[((size_t)e * Kact + gk) * N + gn];
        }
        tile[row_l][col_l] = v;
    }
    __syncthreads();

    const int f = t >> 6, lam = t & 63;
    const int lan = lam & 15, quad = lam >> 4;
    short8 o;
#pragma unroll
    for (int j = 0; j < 8; ++j) {
        int q  = quad * 8 + j;                              // physical k within 32-block
        int sr = inv ? (((q & 1) << 4) | (q >> 1)) : q;     // logical source row
        o[j] = f2b(tile[sr][f * 16 + lan]);
    }
    *(short8*)(out + (size_t)e * PER_E + off +
               ((size_t)(kt * NT + ntb * 4 + f) * 64 + lam) * 8) = o;
}

// One hidden layer. bf0[NTW]: this layer's kt=0 B-frags (prefetched).
// bin[NTW]: this layer's bias values (one per nt, prefetched last layer).
// nbf0[NNTW]/nbin[NNTW]: out — next layer's kt=0 B-frags + bias values,
// prefetched before the epilogue so swish hides the L2 latency.
template<int KT, int NTW, int NT, int NNTW>
__device__ __forceinline__ void mlp_layer(const short* __restrict__ wpk,
                                          short* hs, const int wave, const int lane,
                                          const short8* bf0, const float* bin,
                                          const short* __restrict__ nwpk,
                                          const float* __restrict__ nbias,
                                          short8* nbf0, float* nbin) {
    const int quad = lane >> 4;
    const int lan  = lane & 15;
    floatx4 acc[4][NTW];
#pragma unroll
    for (int mt = 0; mt < 4; ++mt)
#pragma unroll
        for (int nt = 0; nt < NTW; ++nt)
            acc[mt][nt] = floatx4{bin[nt], bin[nt], bin[nt], bin[nt]};  // bias-init

    short8 bfc[NTW], bfn[NTW];
#pragma unroll
    for (int nt = 0; nt < NTW; ++nt) bfc[nt] = bf0[nt];

#pragma unroll
    for (int kt = 0; kt < KT; ++kt) {
        if (kt + 1 < KT) {   // prefetch next kt's B-frags before this kt's MFMAs
#pragma unroll
            for (int nt = 0; nt < NTW; ++nt)
                bfn[nt] = *(const short8*)(wpk +
                    ((size_t)((kt + 1) * NT + wave * NTW + nt) * 64 + lane) * 8);
        }
        short8 af[4];
#pragma unroll
        for (int mt = 0; mt < 4; ++mt)
            af[mt] = *(const short8*)(hs + (mt * 16 + lan) * HSTRIDE + kt * 32 + quad * 8);
#pragma unroll
        for (int nt = 0; nt < NTW; ++nt)
#pragma unroll
            for (int mt = 0; mt < 4; ++mt)
                acc[mt][nt] = __builtin_amdgcn_mfma_f32_16x16x32_bf16(af[mt], bfc[nt], acc[mt][nt], 0, 0, 0);
#pragma unroll
        for (int nt = 0; nt < NTW; ++nt) bfc[nt] = bfn[nt];
    }

    // Prefetch next layer's kt=0 B-frags + bias; epilogue hides the latency.
#pragma unroll
    for (int nt = 0; nt < NNTW; ++nt) {
        nbf0[nt] = *(const short8*)(nwpk + ((size_t)(wave * NNTW + nt) * 64 + lane) * 8);
        nbin[nt] = nbias[(wave * NNTW + nt) * 16 + lan];
    }

    __syncthreads();   // all waves finished reading hs
#pragma unroll
    for (int np = 0; np < NTW / 2; ++np) {
        const int ntg   = wave * NTW + 2 * np;
        const int pcol  = (ntg >> 1) * 32 + 2 * lan;   // pair-interleaved physical col
#pragma unroll
        for (int mt = 0; mt < 4; ++mt)
#pragma unroll
            for (int r2 = 0; r2 < 4; ++r2) {
                float vA = swish(acc[mt][2 * np][r2]);      // bias already in acc
                float vB = swish(acc[mt][2 * np + 1][r2]);
                *(unsigned*)(hs + (mt * 16 + quad * 4 + r2) * HSTRIDE + pcol) = pk2(vA, vB);
            }
    }
    __syncthreads();   // writes visible before next layer reads
}

__global__ void __launch_bounds__(256, 3)
fused_ensemble(const float* __restrict__ state, const float* __restrict__ action,
               const float* __restrict__ b0, const float* __restrict__ b1,
               const float* __restrict__ b2, const float* __restrict__ b3,
               const float* __restrict__ bmu, const float* __restrict__ bsig,
               const float* __restrict__ maxls, const float* __restrict__ minls,
               const short* __restrict__ wpk,
               float* __restrict__ out_mu, float* __restrict__ out_sig) {
    __shared__ __align__(16) short hs[64 * HSTRIDE];
    const int tid  = threadIdx.x;
    const int wave = tid >> 6, lane = tid & 63;
    const int bid  = blockIdx.x;
    const int e    = bid >> 9;      // 512 row-blocks per ensemble
    const int r0   = (bid & 511) << 6;

    const short* wp = wpk + (size_t)e * PER_E;

    // Prefetch L0's kt=0 B-frags + bias; input staging hides the latency.
    short8 fragA[4], fragB[4];
    float  binA[4], binB[4];
#pragma unroll
    for (int nt = 0; nt < 4; ++nt) {
        fragA[nt] = *(const short8*)(wp + ((size_t)(wave * 4 + nt) * 64 + lane) * 8);
        binA[nt]  = b0[e * 256 + (wave * 4 + nt) * 16 + (lane & 15)];
    }

    // Stage input: [state(32) | action(8) | zeros(24)] bf16; float2 -> bf16x2.
    for (int idx = tid; idx < 64 * 32; idx += 256) {   // 64 rows x 32 col-pairs
        int m = idx >> 5, cp = idx & 31;
        int row = r0 + m;
        float2 v;
        if (cp < 16)      v = ((const float2*)state)[row * 16 + cp];
        else if (cp < 20) v = ((const float2*)action)[row * 4 + (cp - 16)];
        else              v = make_float2(0.f, 0.f);
        *(unsigned*)(hs + m * HSTRIDE + 2 * cp) = pk2(v.x, v.y);
    }
    __syncthreads();

    mlp_layer<2, 4, 16, 4>(wp,          hs, wave, lane, fragA, binA, wp + 16384,  b1 + e * 256, fragB, binB);
    mlp_layer<8, 4, 16, 4>(wp + 16384,  hs, wave, lane, fragB, binB, wp + 81920,  b2 + e * 256, fragA, binA);
    mlp_layer<8, 4, 16, 2>(wp + 81920,  hs, wave, lane, fragA, binA, wp + 147456, b3 + e * 128, fragB, binB);

    // Head bias prefetch (per-lane scalar): col = wave*16 + (lane&15) combined.
    const int colw = wave * 16 + (lane & 15);
    const float hbias = (colw < 32) ? bmu[e * 32 + colw] : bsig[e * 32 + (colw - 32)];

    mlp_layer<8, 2, 8, 1 >(wp + 147456, hs, wave, lane, fragB, binB, wp + 180224, b3 /*unused dummy*/, fragA, binA);

    // Heads: K=128, combined N=64 (mu 0..31 | sig 32..63); wave w -> n-tile w.
    const int quad = lane >> 4, lan = lane & 15;
    floatx4 acc[4];
#pragma unroll
    for (int mt = 0; mt < 4; ++mt) acc[mt] = floatx4{hbias, hbias, hbias, hbias};
    const short* wph = wp + 180224;
    short8 bhc = fragA[0], bhn;
#pragma unroll
    for (int kt = 0; kt < 4; ++kt) {
        if (kt < 3)
            bhn = *(const short8*)(wph + (((size_t)(kt + 1) * 4 + wave) * 64 + lane) * 8);
#pragma unroll
        for (int mt = 0; mt < 4; ++mt) {
            const short8 af = *(const short8*)(hs + (mt * 16 + lan) * HSTRIDE + kt * 32 + quad * 8);
            acc[mt] = __builtin_amdgcn_mfma_f32_16x16x32_bf16(af, bhc, acc[mt], 0, 0, 0);
        }
        bhc = bhn;
    }
    if (colw < 32) {                    // mu waves (0,1) — wave-uniform branch
        const int col = colw;
#pragma unroll
        for (int mt = 0; mt < 4; ++mt)
#pragma unroll
            for (int r2 = 0; r2 < 4; ++r2) {
                int grow = r0 + mt * 16 + quad * 4 + r2;
                float v = acc[mt][r2] + state[grow * 32 + col];   // residual (bias in acc)
                out_mu[((size_t)e * NB + grow) * 32 + col] = v;
            }
    } else {                            // sigma waves (2,3)
        const int col = colw - 32;
        const float mx = maxls[col], mn = minls[col];
        const float emx = __expf(mx), emn = __expf(mn);   // once per thread
        // exp(soft_clamp(x,mn,mx)) == e^mn + e^mx / (1 + e^(mx-x))  [exact]
#pragma unroll
        for (int mt = 0; mt < 4; ++mt)
#pragma unroll
            for (int r2 = 0; r2 < 4; ++r2) {
                int grow = r0 + mt * 16 + quad * 4 + r2;
                const float x = acc[mt][r2];               // bias in acc
                const float u = __expf(mx - x);            // inf-safe: rcp(inf)=0
                const float sg = fmaf(emx, __builtin_amdgcn_rcpf(1.f + u), emn);
                out_sig[((size_t)e * NB + grow) * 32 + col] = sg;
            }
    }
}

extern "C" void kernel_launch(void* const* d_in, const int* in_sizes, int n_in,
                              void* d_out, int out_size, void* d_ws, size_t ws_size,
                              hipStream_t stream) {
    const float* state  = (const float*)d_in[0];
    const float* action = (const float*)d_in[1];
    const float* W0   = (const float*)d_in[2];
    const float* b0   = (const float*)d_in[3];
    const float* W1   = (const float*)d_in[4];
    const float* b1   = (const float*)d_in[5];
    const float* W2   = (const float*)d_in[6];
    const float* b2   = (const float*)d_in[7];
    const float* W3   = (const float*)d_in[8];
    const float* b3   = (const float*)d_in[9];
    const float* Wmu  = (const float*)d_in[10];
    const float* bmu  = (const float*)d_in[11];
    const float* Wsig = (const float*)d_in[12];
    const float* bsig = (const float*)d_in[13];
    const float* maxls = (const float*)d_in[14];
    const float* minls = (const float*)d_in[15];

    short* wpk = (short*)d_ws;                         // packed bf16 weights
    float* out_mu  = (float*)d_out;
    float* out_sig = out_mu + (size_t)NE * NB * 32;

    pack_w<<<NE * 92, 256, 0, stream>>>(W0, W1, W2, W3, Wmu, Wsig, wpk);
    fused_ensemble<<<NE * 512, 256, 0, stream>>>(state, action, b0, b1, b2, b3,
                                                 bmu, bsig, maxls, minls, wpk,
                                                 out_mu, out_sig);
}

// Round 12
// 209.683 us; speedup vs baseline: 2.1968x; 1.0052x over previous
//
#include <hip/hip_runtime.h>
#include <hip/hip_bf16.h>

// ---------------------------------------------------------------------------
// EnsembleDynamicModel: E=7 MLPs, B=32768, dims 40->256->256->256->128->(32|32)
// Fully fused bf16-MFMA kernel (R11 structure: bias-preloaded accumulators +
// closed-form sigma head; fused = 129.3us, best).
//
// Round 12: pack_w vectorization; fused kernel byte-identical to R11.
// total(210.8) - fused(129.4) = ~81us is pack_w + launch/harness overhead;
// pack_w was scalar: 8x4B loads + 8 f32-LDS round-trips + 8 manual f2b
// (~70 inst/thread, Common-mistake #2). v2: float4 loads (8->2 VMEM),
// cvt_pk-bf16 BEFORE LDS (32 bit-ops -> 4 cvt_pk), bf16 tile (half LDS
// traffic, uint2 writes). Output layout + RNE rounding identical.
//
// Ledger: R1 spill / R2 LDS-traffic x2 / R3 occupancy / R4 setprio null /
// R5 codegen-invariant / R6 barrier cost / R7 occupancy!=lever / R8
// lgkm-only null / R9 weight-reuse loss / R11 VALU-diet WIN (-15us).
//
// Activation layout: pair-interleaved columns: n-tile ntg col c -> physical
// col 32*(ntg>>1) + 2c + (ntg&1); weight packer applies inverse permutation
// to k for layers reading hidden activations.
// ---------------------------------------------------------------------------

#define NE 7
#define NB 32768
#define PER_E 188416   // packed shorts per ensemble
#define HSTRIDE 264    // 256 + 8 pad (shorts)

typedef __attribute__((ext_vector_type(8))) short short8;   // 8 x bf16
typedef __attribute__((ext_vector_type(4))) float floatx4;  // MFMA C/D

__device__ __forceinline__ unsigned pk2(float a, float b) {  // bf16x2 {lo=a,hi=b}
    union { __hip_bfloat162 h; unsigned u; } c;
    c.h = __float22bfloat162_rn(make_float2(a, b));
    return c.u;
}
__device__ __forceinline__ float swish(float v) {
    return v * __builtin_amdgcn_rcpf(1.f + __expf(-v));
}

// Packed-weight layout per ensemble (units: shorts):
//  L0 : off 0      KT=2 NT=16 Kact=40  N=256
//  L1 : off 16384  KT=8 NT=16 Kact=256 N=256
//  L2 : off 81920  KT=8 NT=16 Kact=256 N=256
//  L3 : off 147456 KT=8 NT=8  Kact=256 N=128
//  HD : off 180224 KT=4 NT=4  Kact=128 N=64   (mu cols 0..31 | sig 32..63)
__global__ void __launch_bounds__(256) pack_w(
    const float* __restrict__ W0, const float* __restrict__ W1,
    const float* __restrict__ W2, const float* __restrict__ W3,
    const float* __restrict__ Wmu, const float* __restrict__ Wsig,
    short* __restrict__ out)
{
    __shared__ __align__(8) short tileb[32][68];   // bf16 tile, 8B-aligned rows
    const int t = threadIdx.x;
    int b = blockIdx.x;
    int e = b / 92;
    int r = b - e * 92;
    const float* src = W0;
    int off = 0, Kact = 40, N = 256, NT = 16, kt, ntb;
    bool inv = false, head = false;
    if (r < 8)       { kt = r >> 2; ntb = r & 3; }
    else if (r < 40) { r -= 8;  src = W1; off = 16384;  Kact = 256; kt = r >> 2; ntb = r & 3; inv = true; }
    else if (r < 72) { r -= 40; src = W2; off = 81920;  Kact = 256; kt = r >> 2; ntb = r & 3; inv = true; }
    else if (r < 88) { r -= 72; src = W3; off = 147456; Kact = 256; N = 128; NT = 8; kt = r >> 1; ntb = r & 1; inv = true; }
    else             { r -= 88; off = 180224; Kact = 128; N = 64; NT = 4; kt = r; ntb = 0; inv = true; head = true; }

#pragma unroll
    for (int i = 0; i < 2; ++i) {                  // 512 float4 per block
        const int e4  = t + i * 256;
        const int row = e4 >> 4;                   // 0..31
        const int c4  = (e4 & 15) << 2;            // 0..60, 16B-aligned cols
        const int gk  = kt * 32 + row;
        const int gn  = ntb * 64 + c4;
        float4 v = make_float4(0.f, 0.f, 0.f, 0.f);
        if (gk < Kact) {
            if (head) v = (gn < 32)
                ? *(const float4*)(Wmu  + ((size_t)e * 128 + gk) * 32 + gn)
                : *(const float4*)(Wsig + ((size_t)e * 128 + gk) * 32 + (gn - 32));
            else      v = *(const float4*)(src + ((size_t)e * Kact + gk) * N + gn);
        }
        *(uint2*)&tileb[row][c4] = make_uint2(pk2(v.x, v.y), pk2(v.z, v.w));
    }
    __syncthreads();

    const int f = t >> 6, lam = t & 63;
    const int lan = lam & 15, quad = lam >> 4;
    short8 o;
#pragma unroll
    for (int j = 0; j < 8; ++j) {
        int q  = quad * 8 + j;                              // physical k within 32-block
        int sr = inv ? (((q & 1) << 4) | (q >> 1)) : q;     // logical source row
        o[j] = tileb[sr][f * 16 + lan];
    }
    *(short8*)(out + (size_t)e * PER_E + off +
               ((size_t)(kt * NT + ntb * 4 + f) * 64 + lam) * 8) = o;
}

// One hidden layer. bf0[NTW]: this layer's kt=0 B-frags (prefetched).
// bin[NTW]: this layer's bias values (one per nt, prefetched last layer).
// nbf0[NNTW]/nbin[NNTW]: out — next layer's kt=0 B-frags + bias values,
// prefetched before the epilogue so swish hides the L2 latency.
template<int KT, int NTW, int NT, int NNTW>
__device__ __forceinline__ void mlp_layer(const short* __restrict__ wpk,
                                          short* hs, const int wave, const int lane,
                                          const short8* bf0, const float* bin,
                                          const short* __restrict__ nwpk,
                                          const float* __restrict__ nbias,
                                          short8* nbf0, float* nbin) {
    const int quad = lane >> 4;
    const int lan  = lane & 15;
    floatx4 acc[4][NTW];
#pragma unroll
    for (int mt = 0; mt < 4; ++mt)
#pragma unroll
        for (int nt = 0; nt < NTW; ++nt)
            acc[mt][nt] = floatx4{bin[nt], bin[nt], bin[nt], bin[nt]};  // bias-init

    short8 bfc[NTW], bfn[NTW];
#pragma unroll
    for (int nt = 0; nt < NTW; ++nt) bfc[nt] = bf0[nt];

#pragma unroll
    for (int kt = 0; kt < KT; ++kt) {
        if (kt + 1 < KT) {   // prefetch next kt's B-frags before this kt's MFMAs
#pragma unroll
            for (int nt = 0; nt < NTW; ++nt)
                bfn[nt] = *(const short8*)(wpk +
                    ((size_t)((kt + 1) * NT + wave * NTW + nt) * 64 + lane) * 8);
        }
        short8 af[4];
#pragma unroll
        for (int mt = 0; mt < 4; ++mt)
            af[mt] = *(const short8*)(hs + (mt * 16 + lan) * HSTRIDE + kt * 32 + quad * 8);
#pragma unroll
        for (int nt = 0; nt < NTW; ++nt)
#pragma unroll
            for (int mt = 0; mt < 4; ++mt)
                acc[mt][nt] = __builtin_amdgcn_mfma_f32_16x16x32_bf16(af[mt], bfc[nt], acc[mt][nt], 0, 0, 0);
#pragma unroll
        for (int nt = 0; nt < NTW; ++nt) bfc[nt] = bfn[nt];
    }

    // Prefetch next layer's kt=0 B-frags + bias; epilogue hides the latency.
#pragma unroll
    for (int nt = 0; nt < NNTW; ++nt) {
        nbf0[nt] = *(const short8*)(nwpk + ((size_t)(wave * NNTW + nt) * 64 + lane) * 8);
        nbin[nt] = nbias[(wave * NNTW + nt) * 16 + lan];
    }

    __syncthreads();   // all waves finished reading hs
#pragma unroll
    for (int np = 0; np < NTW / 2; ++np) {
        const int ntg   = wave * NTW + 2 * np;
        const int pcol  = (ntg >> 1) * 32 + 2 * lan;   // pair-interleaved physical col
#pragma unroll
        for (int mt = 0; mt < 4; ++mt)
#pragma unroll
            for (int r2 = 0; r2 < 4; ++r2) {
                float vA = swish(acc[mt][2 * np][r2]);      // bias already in acc
                float vB = swish(acc[mt][2 * np + 1][r2]);
                *(unsigned*)(hs + (mt * 16 + quad * 4 + r2) * HSTRIDE + pcol) = pk2(vA, vB);
            }
    }
    __syncthreads();   // writes visible before next layer reads
}

__global__ void __launch_bounds__(256, 3)
fused_ensemble(const float* __restrict__ state, const float* __restrict__ action,
               const float* __restrict__ b0, const float* __restrict__ b1,
               const float* __restrict__ b2, const float* __restrict__ b3,
               const float* __restrict__ bmu, const float* __restrict__ bsig,
               const float* __restrict__ maxls, const float* __restrict__ minls,
               const short* __restrict__ wpk,
               float* __restrict__ out_mu, float* __restrict__ out_sig) {
    __shared__ __align__(16) short hs[64 * HSTRIDE];
    const int tid  = threadIdx.x;
    const int wave = tid >> 6, lane = tid & 63;
    const int bid  = blockIdx.x;
    const int e    = bid >> 9;      // 512 row-blocks per ensemble
    const int r0   = (bid & 511) << 6;

    const short* wp = wpk + (size_t)e * PER_E;

    // Prefetch L0's kt=0 B-frags + bias; input staging hides the latency.
    short8 fragA[4], fragB[4];
    float  binA[4], binB[4];
#pragma unroll
    for (int nt = 0; nt < 4; ++nt) {
        fragA[nt] = *(const short8*)(wp + ((size_t)(wave * 4 + nt) * 64 + lane) * 8);
        binA[nt]  = b0[e * 256 + (wave * 4 + nt) * 16 + (lane & 15)];
    }

    // Stage input: [state(32) | action(8) | zeros(24)] bf16; float2 -> bf16x2.
    for (int idx = tid; idx < 64 * 32; idx += 256) {   // 64 rows x 32 col-pairs
        int m = idx >> 5, cp = idx & 31;
        int row = r0 + m;
        float2 v;
        if (cp < 16)      v = ((const float2*)state)[row * 16 + cp];
        else if (cp < 20) v = ((const float2*)action)[row * 4 + (cp - 16)];
        else              v = make_float2(0.f, 0.f);
        *(unsigned*)(hs + m * HSTRIDE + 2 * cp) = pk2(v.x, v.y);
    }
    __syncthreads();

    mlp_layer<2, 4, 16, 4>(wp,          hs, wave, lane, fragA, binA, wp + 16384,  b1 + e * 256, fragB, binB);
    mlp_layer<8, 4, 16, 4>(wp + 16384,  hs, wave, lane, fragB, binB, wp + 81920,  b2 + e * 256, fragA, binA);
    mlp_layer<8, 4, 16, 2>(wp + 81920,  hs, wave, lane, fragA, binA, wp + 147456, b3 + e * 128, fragB, binB);

    // Head bias prefetch (per-lane scalar): col = wave*16 + (lane&15) combined.
    const int colw = wave * 16 + (lane & 15);
    const float hbias = (colw < 32) ? bmu[e * 32 + colw] : bsig[e * 32 + (colw - 32)];

    mlp_layer<8, 2, 8, 1 >(wp + 147456, hs, wave, lane, fragB, binB, wp + 180224, b3 /*unused dummy*/, fragA, binA);

    // Heads: K=128, combined N=64 (mu 0..31 | sig 32..63); wave w -> n-tile w.
    const int quad = lane >> 4, lan = lane & 15;
    floatx4 acc[4];
#pragma unroll
    for (int mt = 0; mt < 4; ++mt) acc[mt] = floatx4{hbias, hbias, hbias, hbias};
    const short* wph = wp + 180224;
    short8 bhc = fragA[0], bhn;
#pragma unroll
    for (int kt = 0; kt < 4; ++kt) {
        if (kt < 3)
            bhn = *(const short8*)(wph + (((size_t)(kt + 1) * 4 + wave) * 64 + lane) * 8);
#pragma unroll
        for (int mt = 0; mt < 4; ++mt) {
            const short8 af = *(const short8*)(hs + (mt * 16 + lan) * HSTRIDE + kt * 32 + quad * 8);
            acc[mt] = __builtin_amdgcn_mfma_f32_16x16x32_bf16(af, bhc, acc[mt], 0, 0, 0);
        }
        bhc = bhn;
    }
    if (colw < 32) {                    // mu waves (0,1) — wave-uniform branch
        const int col = colw;
#pragma unroll
        for (int mt = 0; mt < 4; ++mt)
#pragma unroll
            for (int r2 = 0; r2 < 4; ++r2) {
                int grow = r0 + mt * 16 + quad * 4 + r2;
                float v = acc[mt][r2] + state[grow * 32 + col];   // residual (bias in acc)
                out_mu[((size_t)e * NB + grow) * 32 + col] = v;
            }
    } else {                            // sigma waves (2,3)
        const int col = colw - 32;
        const float mx = maxls[col], mn = minls[col];
        const float emx = __expf(mx), emn = __expf(mn);   // once per thread
        // exp(soft_clamp(x,mn,mx)) == e^mn + e^mx / (1 + e^(mx-x))  [exact]
#pragma unroll
        for (int mt = 0; mt < 4; ++mt)
#pragma unroll
            for (int r2 = 0; r2 < 4; ++r2) {
                int grow = r0 + mt * 16 + quad * 4 + r2;
                const float x = acc[mt][r2];               // bias in acc
                const float u = __expf(mx - x);            // inf-safe: rcp(inf)=0
                const float sg = fmaf(emx, __builtin_amdgcn_rcpf(1.f + u), emn);
                out_sig[((size_t)e * NB + grow) * 32 + col] = sg;
            }
    }
}

extern "C" void kernel_launch(void* const* d_in, const int* in_sizes, int n_in,
                              void* d_out, int out_size, void* d_ws, size_t ws_size,
                              hipStream_t stream) {
    const float* state  = (const float*)d_in[0];
    const float* action = (const float*)d_in[1];
    const float* W0   = (const float*)d_in[2];
    const float* b0   = (const float*)d_in[3];
    const float* W1   = (const float*)d_in[4];
    const float* b1   = (const float*)d_in[5];
    const float* W2   = (const float*)d_in[6];
    const float* b2   = (const float*)d_in[7];
    const float* W3   = (const float*)d_in[8];
    const float* b3   = (const float*)d_in[9];
    const float* Wmu  = (const float*)d_in[10];
    const float* bmu  = (const float*)d_in[11];
    const float* Wsig = (const float*)d_in[12];
    const float* bsig = (const float*)d_in[13];
    const float* maxls = (const float*)d_in[14];
    const float* minls = (const float*)d_in[15];

    short* wpk = (short*)d_ws;                         // packed bf16 weights
    float* out_mu  = (float*)d_out;
    float* out_sig = out_mu + (size_t)NE * NB * 32;

    pack_w<<<NE * 92, 256, 0, stream>>>(W0, W1, W2, W3, Wmu, Wsig, wpk);
    fused_ensemble<<<NE * 512, 256, 0, stream>>>(state, action, b0, b1, b2, b3,
                                                 bmu, bsig, maxls, minls, wpk,
                                                 out_mu, out_sig);
}